// Round 10
// baseline (324.957 us; speedup 1.0000x reference)
//
#include <hip/hip_runtime.h>
#include <hip/hip_bf16.h>

#define HC    256
#define FIN   32
#define NH    8
#define GROUP 8     // dst nodes per block (2 per wave)
#define CAPW  32    // per-wave staged edges per chunk

typedef __hip_bfloat16 bf16;

__device__ __forceinline__ float blo(unsigned int u) { return __uint_as_float(u << 16); }
__device__ __forceinline__ float bhi(unsigned int u) { return __uint_as_float(u & 0xffff0000u); }
__device__ __forceinline__ unsigned int pk2(float a, float b) {
  bf16 ha = __float2bfloat16(a), hb = __float2bfloat16(b);
  unsigned short ua, ub;
  __builtin_memcpy(&ua, &ha, 2); __builtin_memcpy(&ub, &hb, 2);
  return (unsigned int)ua | ((unsigned int)ub << 16);
}
__device__ __forceinline__ short bfs(float v) {
  bf16 h = __float2bfloat16(v);
  short s; __builtin_memcpy(&s, &h, 2);
  return s;
}

// ---------------- CSR build ---------------------------------------------------
// blocks [0,eb): count + per-edge rank (coalesced ord write).
// block eb: folded weight prep + bf16 conversion of W1/W2 (independent).
// Mbuf floats: [0:64) M1 | [64:128) M2 | [128:384) P1s | [384:640) P1d
//              | [640:896) P2s | [896:1152) P2d
__global__ void count_fold_kernel(const int* __restrict__ dst, int* __restrict__ cnt,
                                  int* __restrict__ ord, int E_, int eb,
                                  const float* __restrict__ We1, const float* __restrict__ ae1,
                                  const float* __restrict__ We2, const float* __restrict__ ae2,
                                  const float* __restrict__ W1, const float* __restrict__ as1,
                                  const float* __restrict__ ad1,
                                  const float* __restrict__ W2, const float* __restrict__ as2,
                                  const float* __restrict__ ad2,
                                  float* __restrict__ M,
                                  bf16* __restrict__ w1bf, bf16* __restrict__ w2bf) {
  if (blockIdx.x < (unsigned)eb) {
    int e = blockIdx.x * blockDim.x + threadIdx.x;
    if (e < E_) ord[e] = atomicAdd(&cnt[dst[e]], 1);
  } else {
    for (int idx = threadIdx.x; idx < 1152; idx += 256) {
      const float* A; const float* V; int i;
      if (idx < 64)       { i = idx;       A = We1; V = ae1; }
      else if (idx < 128) { i = idx - 64;  A = We2; V = ae2; }
      else if (idx < 384) { i = idx - 128; A = W1;  V = as1; }
      else if (idx < 640) { i = idx - 384; A = W1;  V = ad1; }
      else if (idx < 896) { i = idx - 640; A = W2;  V = as2; }
      else                { i = idx - 896; A = W2;  V = ad2; }
      int k = i >> 3, h = i & 7;
      float s = 0.f;
      for (int c = 0; c < FIN; ++c)
        s = fmaf(A[k * HC + h * FIN + c], V[h * FIN + c], s);
      M[idx] = s;
    }
    // bf16 copies of W1/W2 [32][256] for the MFMA epilogue in agg
    for (int idx = threadIdx.x; idx < FIN * HC; idx += 256) {
      w1bf[idx] = __float2bfloat16(W1[idx]);
      w2bf[idx] = __float2bfloat16(W2[idx]);
    }
  }
}

// scan step 1: per-256-tile inclusive prefix (into tmp) + raw tile sums (bsum)
__global__ __launch_bounds__(256) void
scan_partial(const int* __restrict__ cnt, int* __restrict__ tmp,
             int* __restrict__ bsum, int N_) {
  __shared__ int part[256];
  int t = threadIdx.x, i = blockIdx.x * 256 + t;
  int v = (i < N_) ? cnt[i] : 0;
  part[t] = v;
  __syncthreads();
#pragma unroll
  for (int off = 1; off < 256; off <<= 1) {
    int u = (t >= off) ? part[t - off] : 0;
    __syncthreads();
    part[t] += u;
    __syncthreads();
  }
  if (i < N_) tmp[i] = part[t];
  if (t == 255) bsum[blockIdx.x] = part[255];
}

// scan step 2 (fused): each block reduces bsum[0..bid) itself, then
// rowptr[i] = boff + incl[i] - cnt[i]; rowptr[N]=E. (NB <= ~1024 is cheap.)
__global__ __launch_bounds__(256) void
scan_final(const int* __restrict__ cnt, const int* __restrict__ tmp,
           const int* __restrict__ bsum, int* __restrict__ rowptr,
           int N_, int E_, int NB) {
  __shared__ int red[256];
  int t = threadIdx.x, b = blockIdx.x;
  int acc = 0;
  for (int j = t; j < b; j += 256) acc += bsum[j];
  red[t] = acc;
  __syncthreads();
#pragma unroll
  for (int off = 128; off > 0; off >>= 1) {
    if (t < off) red[t] += red[t + off];
    __syncthreads();
  }
  int boff = red[0];
  int i = b * 256 + t;
  if (i < N_) rowptr[i] = boff + tmp[i] - cnt[i];
  if (i == 0) rowptr[N_] = E_;
}

// scatter-lite (no atomics, ONE 8B scattered write/edge) + fused layer-1 prep.
// Blocks [0, eb): se[pos] = {src[e], e}. Blocks [eb, eb+pb): prep1.
__global__ __launch_bounds__(256) void
scatter_prep_kernel(const int* __restrict__ src, const int* __restrict__ dst,
                    const int* __restrict__ rowptr, const int* __restrict__ ord,
                    int2* __restrict__ se,
                    const float* __restrict__ M,
                    const float* __restrict__ emb, const int* __restrict__ node_ids,
                    bf16* __restrict__ xq, float* __restrict__ alsrc,
                    float* __restrict__ aldst,
                    int E_, int N_, int eb) {
  __shared__ float xs[8][33];
  int t = threadIdx.x;
  if (blockIdx.x < (unsigned)eb) {
    int e = blockIdx.x * 256 + t;
    if (e < E_) {
      int pos = rowptr[dst[e]] + ord[e];
      se[pos] = make_int2(src[e], e);   // single 8B scattered write
    }
  } else {
    // ---- prep1: xq1 = bf16(emb[node_ids]); alsrc1/aldst1 = x @ P1 ----
    const float* P = M + 128;
    int n0 = (blockIdx.x - eb) * 8;
    int nl = t >> 5, c = t & 31;
    int n = n0 + nl;
    if (n < N_) {
      float v = emb[(size_t)node_ids[n] * FIN + c];
      xq[(size_t)n * FIN + c] = __float2bfloat16(v);
      xs[nl][c] = v;
    }
    __syncthreads();
    if (t < 64) {
      int nl2 = t >> 3, h = t & 7;
      int n2 = n0 + nl2;
      if (n2 < N_) {
        float sa = 0.f, sd = 0.f;
#pragma unroll
        for (int k = 0; k < FIN; ++k) {
          float x = xs[nl2][k];
          sa = fmaf(x, P[k * 8 + h], sa);
          sd = fmaf(x, P[256 + k * 8 + h], sd);
        }
        alsrc[(size_t)n2 * NH + h] = sa;
        aldst[(size_t)n2 * NH + h] = sd;
      }
    }
  }
}

// pos-order pass: gather edge_attr[e] ONCE (random), fold with M, write
// srcs + per-layer packed bf16 records COALESCED (16B each layer).
__global__ __launch_bounds__(256) void
alepk_build_kernel(const int2* __restrict__ se, const float* __restrict__ edge_attr,
                   const float* __restrict__ M,
                   int* __restrict__ srcs, unsigned int* __restrict__ ale1pk,
                   unsigned int* __restrict__ ale2pk, int E_) {
  __shared__ float Msh[128];
  int t = threadIdx.x;
  if (t < 128) Msh[t] = M[t];
  __syncthreads();
  int pos = blockIdx.x * 256 + t;
  if (pos >= E_) return;
  int2 s2 = se[pos];               // coalesced 8B read
  srcs[pos] = s2.x;                // coalesced 4B write
  int e = s2.y;
  const float4* ep = (const float4*)(edge_attr + (size_t)e * NH);  // 32B gather
  float4 a0 = ep[0], a1 = ep[1];
  float ea[8] = {a0.x, a0.y, a0.z, a0.w, a1.x, a1.y, a1.z, a1.w};
  float o1[8], o2[8];
#pragma unroll
  for (int h = 0; h < 8; ++h) { o1[h] = 0.f; o2[h] = 0.f; }
#pragma unroll
  for (int k = 0; k < 8; ++k) {
    float x = ea[k];
#pragma unroll
    for (int h = 0; h < 8; ++h) {
      o1[h] = fmaf(x, Msh[k * 8 + h], o1[h]);
      o2[h] = fmaf(x, Msh[64 + k * 8 + h], o2[h]);
    }
  }
  uint4 r0 = make_uint4(pk2(o1[0], o1[1]), pk2(o1[2], o1[3]),
                        pk2(o1[4], o1[5]), pk2(o1[6], o1[7]));
  uint4 r1 = make_uint4(pk2(o2[0], o2[1]), pk2(o2[2], o2[3]),
                        pk2(o2[4], o2[5]), pk2(o2[6], o2[7]));
  *(uint4*)(ale1pk + (size_t)pos * 4) = r0;   // coalesced 16B write
  *(uint4*)(ale2pk + (size_t)pos * 4) = r1;   // coalesced 16B write
}

// ---- fused agg: BARRIER-FREE main loop + MFMA z@W epilogue ------------------
// Main loop identical to the verified R7/R9 structure. Epilogue z@W is 8
// per-head GEMMs G_h[8x32] = Z_h[8x32] @ W[:, h*32:(h+1)*32], computed with
// v_mfma_f32_16x16x32_bf16: wave w does heads 2w,2w+1; per head 2 col-tiles.
// A-frag: lane l holds A[row=l&15][k=(l>>4)*8+j]; B-frag: B[k=(l>>4)*8+j][col=l&15];
// D: row=(l>>4)*4+r, col=l&15 (C/D mapping HW-verified in reference).
template <int K, int LOG2K, bool LOGITS>
__global__ __launch_bounds__(256, 8) void
agg_kernel(const int* __restrict__ rowptr, const int* __restrict__ srcs,
           const bf16* __restrict__ ale,
           const float* __restrict__ alsrc, const float* __restrict__ aldst,
           const bf16* __restrict__ xq,
           const bf16* __restrict__ Wbf, const float* __restrict__ b,
           const float* __restrict__ Wlin, const float* __restrict__ blin,
           float* __restrict__ xoutf, bf16* __restrict__ xqn,
           const float* __restrict__ Pn,
           float* __restrict__ alsrcn, float* __restrict__ aldstn, int N_) {
  __shared__ __align__(16) char smem[17408];
  unsigned int* xsu = (unsigned int*)smem;
  float* wsf   = (float*)(smem + 8192);
  float* ald_s = (float*)(smem + 12288);
  float* zs   = (float*)smem;
  float* gs   = (float*)(smem + 8192);
  float* red  = (float*)smem;
  float* xrow = (float*)(smem + 16384);

  int t = threadIdx.x;
  int n0 = blockIdx.x * GROUP;
  int w = t >> 6, l = t & 63, h = l >> 3, q = l & 7;

  unsigned int* xw  = xsu + w * 512;
  float*        wsw = wsf + w * 256;
  char* xwb = smem + w * 2048;     // wave-uniform LDS base for staging

  // this wave's two nodes' edge ranges (wave-uniform scalars)
  int nA = n0 + w * 2;
  int e0  = rowptr[(nA     <= N_) ? nA     : N_];
  int e1  = rowptr[(nA + 1 <= N_) ? nA + 1 : N_];
  int e2g = rowptr[(nA + 2 <= N_) ? nA + 2 : N_];

  if (t < GROUP * NH) {
    int nn = n0 + (t >> 3);
    ald_s[t] = (nn < N_) ? aldst[(size_t)nn * NH + (t & 7)] : 0.f;
  }
  __syncthreads();   // ald_s visible to all waves (read-only afterwards)

  float4 acc0 = make_float4(0.f, 0.f, 0.f, 0.f);
  float4 acc1 = make_float4(0.f, 0.f, 0.f, 0.f);
  float dn0 = 0.f, dn1 = 0.f;

  for (int cbeg = e0; cbeg < e2g; cbeg += CAPW) {
    int clen = e2g - cbeg; if (clen > CAPW) clen = CAPW;

    // stage x rows: 2 passes of 16 edges via global_load_lds (16B/lane)
    {
      int el0 = (l >> 2);
      int coff = (l & 3);
      int ec0 = el0 < clen - 1 ? el0 : clen - 1;          // clamp keeps lanes active
      {
        int s = srcs[cbeg + ec0];
        const bf16* gp = xq + (size_t)s * FIN + coff * 8;
        __builtin_amdgcn_global_load_lds(
            (const __attribute__((address_space(1))) void*)gp,
            (__attribute__((address_space(3))) void*)xwb, 16, 0, 0);
      }
      if (clen > 16) {
        int el1 = 16 + el0;
        int ec1 = el1 < clen - 1 ? el1 : clen - 1;
        int s = srcs[cbeg + ec1];
        const bf16* gp = xq + (size_t)s * FIN + coff * 8;
        __builtin_amdgcn_global_load_lds(
            (const __attribute__((address_space(1))) void*)gp,
            (__attribute__((address_space(3))) void*)(xwb + 1024), 16, 0, 0);
      }
    }
    // stage exp(alpha): 2 lanes/edge; al_e from packed bf16 record (coalesced)
    {
      int e2 = l >> 1, half = l & 1;
      if (e2 < clen) {
        int j = cbeg + e2;
        int ii = (j >= e1) ? 1 : 0;
        int sn = srcs[j];
        uint2 ue  = *(const uint2*)(ale + (size_t)j * 8 + half * 4);
        float4 as4 = *(const float4*)(alsrc + (size_t)sn * NH + half * 4);
        float4 ad4 = *(const float4*)&ald_s[(w * 2 + ii) * 8 + half * 4];
        float a0f = blo(ue.x) + as4.x + ad4.x; a0f = (a0f >= 0.f) ? a0f : 0.2f * a0f;
        float a1f = bhi(ue.x) + as4.y + ad4.y; a1f = (a1f >= 0.f) ? a1f : 0.2f * a1f;
        float a2f = blo(ue.y) + as4.z + ad4.z; a2f = (a2f >= 0.f) ? a2f : 0.2f * a2f;
        float a3f = bhi(ue.y) + as4.w + ad4.w; a3f = (a3f >= 0.f) ? a3f : 0.2f * a3f;
        *(float4*)&wsw[e2 * 8 + half * 4] =
            make_float4(__expf(a0f), __expf(a1f), __expf(a2f), __expf(a3f));
      }
    }
    // wave-local fence: staged x (vmcnt) + exp writes (lgkmcnt) before reads
    asm volatile("s_waitcnt vmcnt(0) lgkmcnt(0)" ::: "memory");

    // FMA: this wave sweeps its staged edges (broadcast LDS reads)
    int hA = e1 - cbeg; if (hA < 0) hA = 0; if (hA > clen) hA = clen;
#pragma unroll 4
    for (int le = 0; le < hA; ++le) {
      float wv = wsw[le * 8 + h];
      uint2 u = *(const uint2*)&xw[le * 16 + q * 2];
      acc0.x = fmaf(blo(u.x), wv, acc0.x);
      acc0.y = fmaf(bhi(u.x), wv, acc0.y);
      acc0.z = fmaf(blo(u.y), wv, acc0.z);
      acc0.w = fmaf(bhi(u.y), wv, acc0.w);
      dn0 += wv;
    }
#pragma unroll 4
    for (int le = hA; le < clen; ++le) {
      float wv = wsw[le * 8 + h];
      uint2 u = *(const uint2*)&xw[le * 16 + q * 2];
      acc1.x = fmaf(blo(u.x), wv, acc1.x);
      acc1.y = fmaf(bhi(u.x), wv, acc1.y);
      acc1.z = fmaf(blo(u.y), wv, acc1.z);
      acc1.w = fmaf(bhi(u.y), wv, acc1.w);
      dn1 += wv;
    }
    asm volatile("s_waitcnt lgkmcnt(0)" ::: "memory");  // reads done before restage
  }

  // normalize + write z (lands in this wave's own staging slice — safe)
  float rd0 = 1.0f / (dn0 + 1e-16f);
  float rd1 = 1.0f / (dn1 + 1e-16f);
  *(float4*)&zs[(w * 2 + 0) * 256 + l * 4] =
      make_float4(acc0.x * rd0, acc0.y * rd0, acc0.z * rd0, acc0.w * rd0);
  *(float4*)&zs[(w * 2 + 1) * 256 + l * 4] =
      make_float4(acc1.x * rd1, acc1.y * rd1, acc1.z * rd1, acc1.w * rd1);
  __syncthreads();

  // g = relu(z @ W + b) via MFMA: wave w -> heads 2w, 2w+1; 2 col-tiles each.
  {
    typedef __attribute__((ext_vector_type(8))) short short8v;
    typedef __attribute__((ext_vector_type(4))) float f32x4v;
    int row = l & 15, seg = l >> 4;          // A/D row (node), k-segment
#pragma unroll
    for (int hh2 = 0; hh2 < 2; ++hh2) {
      int hh = w * 2 + hh2;
      short8v af;
#pragma unroll
      for (int j = 0; j < 8; ++j) {
        float zv = (row < GROUP) ? zs[row * 256 + hh * 32 + seg * 8 + j] : 0.f;
        af[j] = bfs(zv);
      }
#pragma unroll
      for (int n2 = 0; n2 < 2; ++n2) {
        short8v bfv;
#pragma unroll
        for (int j = 0; j < 8; ++j) {
          bf16 wv = Wbf[(size_t)(seg * 8 + j) * HC + hh * 32 + n2 * 16 + row];
          short sv; __builtin_memcpy(&sv, &wv, 2);
          bfv[j] = sv;
        }
        f32x4v d = {0.f, 0.f, 0.f, 0.f};
        d = __builtin_amdgcn_mfma_f32_16x16x32_bf16(af, bfv, d, 0, 0, 0);
#pragma unroll
        for (int r = 0; r < 4; ++r) {
          int rd = seg * 4 + r;
          if (rd < GROUP) {
            int tc = hh * 32 + n2 * 16 + row;
            float gv = d[r] + b[tc];
            gs[rd * 256 + tc] = (gv > 0.f) ? gv : 0.f;
          }
        }
      }
    }
  }
  __syncthreads();

  // lin: xout = g @ Wlin + blin (Wlin element reused x GROUP); red aliases zs (dead)
  {
    int kk = t & (K - 1), r = t >> LOG2K;
    float part[GROUP];
#pragma unroll
    for (int i = 0; i < GROUP; ++i) part[i] = 0.f;
#pragma unroll
    for (int j4 = 0; j4 < K / 4; ++j4) {
      float ga[GROUP][4];
#pragma unroll
      for (int i = 0; i < GROUP; ++i)
        *(float4*)ga[i] = *(const float4*)&gs[i * 256 + r * K + j4 * 4];
#pragma unroll
      for (int jj = 0; jj < 4; ++jj) {
        float wl = Wlin[(r * K + j4 * 4 + jj) * K + kk];
#pragma unroll
        for (int i = 0; i < GROUP; ++i) part[i] = fmaf(ga[i][jj], wl, part[i]);
      }
    }
#pragma unroll
    for (int i = 0; i < GROUP; ++i) red[i * 256 + t] = part[i];
  }
  __syncthreads();

  if (LOGITS) {
    if (t < GROUP * 32) {
      int i = t >> 5, kk = t & 31;
      float s = blin[kk];
#pragma unroll
      for (int r2 = 0; r2 < HC / K; ++r2) s += red[i * 256 + r2 * K + kk];
      int nn = n0 + i;
      if (nn < N_) xqn[(size_t)nn * FIN + kk] = __float2bfloat16(s);
      xrow[t] = s;
    }
    __syncthreads();
    if (t < GROUP * NH) {
      int i = t >> 3, hh = t & 7;
      int nn = n0 + i;
      if (nn < N_) {
        float sa = 0.f, sd = 0.f;
#pragma unroll
        for (int k2 = 0; k2 < FIN; ++k2) {
          float x = xrow[i * 32 + k2];
          sa = fmaf(x, Pn[k2 * 8 + hh], sa);
          sd = fmaf(x, Pn[256 + k2 * 8 + hh], sd);
        }
        alsrcn[(size_t)nn * NH + hh] = sa;
        aldstn[(size_t)nn * NH + hh] = sd;
      }
    }
  } else {
    if (t < GROUP * K) {
      int i = t >> LOG2K, kk = t & (K - 1);
      float s = blin[kk];
#pragma unroll
      for (int r2 = 0; r2 < HC / K; ++r2) s += red[i * 256 + r2 * K + kk];
      int nn = n0 + i;
      if (nn < N_) xoutf[(size_t)nn * K + kk] = s;
    }
  }
}

// ---------------- classifier: sigmoid(sum(fu*fm)) ----------------------------
__global__ void clf_kernel(const int* __restrict__ eli, const float* __restrict__ ela,
                           const float* __restrict__ x2, const float* __restrict__ clfW,
                           const float* __restrict__ clfb, float* __restrict__ out, int L_) {
  int i = blockIdx.x * blockDim.x + threadIdx.x;
  if (i >= L_) return;
  int u = eli[i], m = eli[L_ + i];
  const float4* xup = (const float4*)(x2 + (size_t)u * NH);
  const float4* xmp = (const float4*)(x2 + (size_t)m * NH);
  const float4* eap = (const float4*)(ela + (size_t)i * NH);
  float4 xu0 = xup[0], xu1 = xup[1];
  float4 xm0 = xmp[0], xm1 = xmp[1];
  float4 el0 = eap[0], el1 = eap[1];
  float xu[NH] = {xu0.x, xu0.y, xu0.z, xu0.w, xu1.x, xu1.y, xu1.z, xu1.w};
  float xm[NH] = {xm0.x, xm0.y, xm0.z, xm0.w, xm1.x, xm1.y, xm1.z, xm1.w};
  float el[NH] = {el0.x, el0.y, el0.z, el0.w, el1.x, el1.y, el1.z, el1.w};
  float fu[NH];
#pragma unroll
  for (int kk = 0; kk < NH; ++kk) fu[kk] = clfb[kk];
#pragma unroll
  for (int j = 0; j < NH; ++j) {
#pragma unroll
    for (int kk = 0; kk < NH; ++kk) fu[kk] = fmaf(xu[j], clfW[j * NH + kk], fu[kk]);
  }
#pragma unroll
  for (int j = 0; j < NH; ++j) {
#pragma unroll
    for (int kk = 0; kk < NH; ++kk) fu[kk] = fmaf(el[j], clfW[(NH + j) * NH + kk], fu[kk]);
  }
  float dot = 0.f;
#pragma unroll
  for (int kk = 0; kk < NH; ++kk) dot += fu[kk] * xm[kk];
  out[i] = 1.f / (1.f + __expf(-dot));
}

extern "C" void kernel_launch(void* const* d_in, const int* in_sizes, int n_in,
                              void* d_out, int out_size, void* d_ws, size_t ws_size,
                              hipStream_t stream) {
  const int* node_ids   = (const int*)d_in[0];
  const int* edge_index = (const int*)d_in[1];
  const int* eli        = (const int*)d_in[2];
  const float* edge_attr = (const float*)d_in[4];
  const float* ela       = (const float*)d_in[5];
  const float* emb       = (const float*)d_in[6];
  const float* W1     = (const float*)d_in[7];
  const float* a_src1 = (const float*)d_in[8];
  const float* a_dst1 = (const float*)d_in[9];
  const float* We1    = (const float*)d_in[10];
  const float* a_e1   = (const float*)d_in[11];
  const float* b1     = (const float*)d_in[12];
  const float* lin1W  = (const float*)d_in[13];
  const float* lin1b  = (const float*)d_in[14];
  const float* W2     = (const float*)d_in[15];
  const float* a_src2 = (const float*)d_in[16];
  const float* a_dst2 = (const float*)d_in[17];
  const float* We2    = (const float*)d_in[18];
  const float* a_e2   = (const float*)d_in[19];
  const float* b2     = (const float*)d_in[20];
  const float* lin5W  = (const float*)d_in[21];
  const float* lin5b  = (const float*)d_in[22];
  const float* clfW   = (const float*)d_in[23];
  const float* clfb   = (const float*)d_in[24];

  const int N_ = in_sizes[0];
  const int E_ = in_sizes[1] / 2;
  const int L_ = in_sizes[2] / 2;
  const int* src  = edge_index;
  const int* dstp = edge_index + E_;

  char* p = (char*)d_ws;
  auto carve = [&](size_t bytes) -> char* {
    char* r = p;
    p += (bytes + 255) & ~(size_t)255;
    return r;
  };
  bf16*  xq1     = (bf16*)carve((size_t)N_ * FIN * 2);
  bf16*  xq2     = (bf16*)carve((size_t)N_ * FIN * 2);
  unsigned int* ale1pk = (unsigned int*)carve((size_t)E_ * 16);  // 12.8 MB packed bf16
  unsigned int* ale2pk = (unsigned int*)carve((size_t)E_ * 16);  // 12.8 MB packed bf16
  float* alsrc1  = (float*)carve((size_t)N_ * NH * 4);
  float* aldst1  = (float*)carve((size_t)N_ * NH * 4);
  float* alsrc2  = (float*)carve((size_t)N_ * NH * 4);
  float* aldst2  = (float*)carve((size_t)N_ * NH * 4);
  float* x2b     = (float*)carve((size_t)N_ * NH * 4);
  float* Mbuf    = (float*)carve(1152 * 4);
  bf16*  w1bf    = (bf16*)carve((size_t)FIN * HC * 2);
  bf16*  w2bf    = (bf16*)carve((size_t)FIN * HC * 2);
  int*   cnt     = (int*)carve((size_t)N_ * 4);
  int*   rowptr  = (int*)carve((size_t)(N_ + 1) * 4);
  int*   stmp    = (int*)carve((size_t)N_ * 4);
  int*   bsum    = (int*)carve(1024 * 4);
  int*   srcs    = (int*)carve((size_t)E_ * 4);
  int*   ordb    = (int*)carve((size_t)E_ * 4);
  int2*  se      = (int2*)carve((size_t)E_ * 8);

  hipMemsetAsync(cnt, 0, (size_t)N_ * 4, stream);
  int eb = (E_ + 255) / 256;
  int nb = (N_ + 255) / 256;
  int pb = (N_ + 7) / 8;
  count_fold_kernel<<<eb + 1, 256, 0, stream>>>(dstp, cnt, ordb, E_, eb,
                                                We1, a_e1, We2, a_e2,
                                                W1, a_src1, a_dst1,
                                                W2, a_src2, a_dst2, Mbuf,
                                                w1bf, w2bf);
  scan_partial<<<nb, 256, 0, stream>>>(cnt, stmp, bsum, N_);
  scan_final<<<nb, 256, 0, stream>>>(cnt, stmp, bsum, rowptr, N_, E_, nb);
  scatter_prep_kernel<<<eb + pb, 256, 0, stream>>>(
      src, dstp, rowptr, ordb, se, Mbuf,
      emb, node_ids, xq1, alsrc1, aldst1, E_, N_, eb);
  alepk_build_kernel<<<eb, 256, 0, stream>>>(se, edge_attr, Mbuf, srcs,
                                             ale1pk, ale2pk, E_);

  int gb = (N_ + GROUP - 1) / GROUP;
  // ---- layer 1 (fully fused) ----
  agg_kernel<32, 5, true><<<gb, 256, 0, stream>>>(
      rowptr, srcs, (const bf16*)ale1pk, alsrc1, aldst1, xq1,
      w1bf, b1, lin1W, lin1b, nullptr, xq2, Mbuf + 640, alsrc2, aldst2, N_);

  // ---- layer 2 ----
  agg_kernel<8, 3, false><<<gb, 256, 0, stream>>>(
      rowptr, srcs, (const bf16*)ale2pk, alsrc2, aldst2, xq2,
      w2bf, b2, lin5W, lin5b, x2b, nullptr, nullptr, nullptr, nullptr, N_);

  // ---- classifier ----
  clf_kernel<<<(L_ + 255) / 256, 256, 0, stream>>>(eli, ela, x2b, clfW, clfb,
                                                   (float*)d_out, L_);
}

// Round 11
// 318.552 us; speedup vs baseline: 1.0201x; 1.0201x over previous
//
#include <hip/hip_runtime.h>
#include <hip/hip_bf16.h>

#define HC    256
#define FIN   32
#define NH    8
#define GROUP 8     // dst nodes per block (2 per wave)
#define CAPW  32    // per-wave staged edges per chunk

typedef __hip_bfloat16 bf16;

__device__ __forceinline__ float blo(unsigned int u) { return __uint_as_float(u << 16); }
__device__ __forceinline__ float bhi(unsigned int u) { return __uint_as_float(u & 0xffff0000u); }
__device__ __forceinline__ unsigned int pk2(float a, float b) {
  bf16 ha = __float2bfloat16(a), hb = __float2bfloat16(b);
  unsigned short ua, ub;
  __builtin_memcpy(&ua, &ha, 2); __builtin_memcpy(&ub, &hb, 2);
  return (unsigned int)ua | ((unsigned int)ub << 16);
}
__device__ __forceinline__ short bfs(float v) {
  bf16 h = __float2bfloat16(v);
  short s; __builtin_memcpy(&s, &h, 2);
  return s;
}

// ---------------- CSR build ---------------------------------------------------
// blocks [0,eb): count + per-edge rank (coalesced ord write).
// block eb: folded weight prep + FRAGMENT-ORDERED bf16 W for the MFMA epilogue.
// wfrag layout: [tile=hh*2+n2][lane=seg*16+row][j=0..7] bf16, value =
//   W[(seg*8+j)*HC + hh*32 + n2*16 + row]  (B-frag: lane l holds
//   B[k=(l>>4)*8+j][col=l&15] for v_mfma_f32_16x16x32_bf16 — layout verified
//   numerically in R10: absmax unchanged).
__global__ void count_fold_kernel(const int* __restrict__ dst, int* __restrict__ cnt,
                                  int* __restrict__ ord, int E_, int eb,
                                  const float* __restrict__ We1, const float* __restrict__ ae1,
                                  const float* __restrict__ We2, const float* __restrict__ ae2,
                                  const float* __restrict__ W1, const float* __restrict__ as1,
                                  const float* __restrict__ ad1,
                                  const float* __restrict__ W2, const float* __restrict__ as2,
                                  const float* __restrict__ ad2,
                                  float* __restrict__ M,
                                  bf16* __restrict__ w1frag, bf16* __restrict__ w2frag) {
  if (blockIdx.x < (unsigned)eb) {
    int e = blockIdx.x * blockDim.x + threadIdx.x;
    if (e < E_) ord[e] = atomicAdd(&cnt[dst[e]], 1);
  } else {
    for (int idx = threadIdx.x; idx < 1152; idx += 256) {
      const float* A; const float* V; int i;
      if (idx < 64)       { i = idx;       A = We1; V = ae1; }
      else if (idx < 128) { i = idx - 64;  A = We2; V = ae2; }
      else if (idx < 384) { i = idx - 128; A = W1;  V = as1; }
      else if (idx < 640) { i = idx - 384; A = W1;  V = ad1; }
      else if (idx < 896) { i = idx - 640; A = W2;  V = as2; }
      else                { i = idx - 896; A = W2;  V = ad2; }
      int k = i >> 3, h = i & 7;
      float s = 0.f;
      for (int c = 0; c < FIN; ++c)
        s = fmaf(A[k * HC + h * FIN + c], V[h * FIN + c], s);
      M[idx] = s;
    }
    // fragment-ordered bf16 W1/W2 (16 tiles x 64 lanes x 8 = 8192 elems each)
    for (int idx = threadIdx.x; idx < 8192; idx += 256) {
      int j = idx & 7, lane = (idx >> 3) & 63, tile = idx >> 9;
      int seg = lane >> 4, row = lane & 15;
      int hh = tile >> 1, n2 = tile & 1;
      int k = seg * 8 + j, col = hh * 32 + n2 * 16 + row;
      w1frag[idx] = __float2bfloat16(W1[k * HC + col]);
      w2frag[idx] = __float2bfloat16(W2[k * HC + col]);
    }
  }
}

// scan step 1: per-256-tile inclusive prefix (into tmp) + raw tile sums (bsum)
__global__ __launch_bounds__(256) void
scan_partial(const int* __restrict__ cnt, int* __restrict__ tmp,
             int* __restrict__ bsum, int N_) {
  __shared__ int part[256];
  int t = threadIdx.x, i = blockIdx.x * 256 + t;
  int v = (i < N_) ? cnt[i] : 0;
  part[t] = v;
  __syncthreads();
#pragma unroll
  for (int off = 1; off < 256; off <<= 1) {
    int u = (t >= off) ? part[t - off] : 0;
    __syncthreads();
    part[t] += u;
    __syncthreads();
  }
  if (i < N_) tmp[i] = part[t];
  if (t == 255) bsum[blockIdx.x] = part[255];
}

// scan step 2 (fused): each block reduces bsum[0..bid) itself, then
// rowptr[i] = boff + incl[i] - cnt[i]; rowptr[N]=E. (NB <= ~1024 is cheap.)
__global__ __launch_bounds__(256) void
scan_final(const int* __restrict__ cnt, const int* __restrict__ tmp,
           const int* __restrict__ bsum, int* __restrict__ rowptr,
           int N_, int E_, int NB) {
  __shared__ int red[256];
  int t = threadIdx.x, b = blockIdx.x;
  int acc = 0;
  for (int j = t; j < b; j += 256) acc += bsum[j];
  red[t] = acc;
  __syncthreads();
#pragma unroll
  for (int off = 128; off > 0; off >>= 1) {
    if (t < off) red[t] += red[t + off];
    __syncthreads();
  }
  int boff = red[0];
  int i = b * 256 + t;
  if (i < N_) rowptr[i] = boff + tmp[i] - cnt[i];
  if (i == 0) rowptr[N_] = E_;
}

// scatter-lite (no atomics, ONE 8B scattered write/edge) + fused layer-1 prep.
// Blocks [0, eb): se[pos] = {src[e], e}. Blocks [eb, eb+pb): prep1.
__global__ __launch_bounds__(256) void
scatter_prep_kernel(const int* __restrict__ src, const int* __restrict__ dst,
                    const int* __restrict__ rowptr, const int* __restrict__ ord,
                    int2* __restrict__ se,
                    const float* __restrict__ M,
                    const float* __restrict__ emb, const int* __restrict__ node_ids,
                    bf16* __restrict__ xq, float* __restrict__ alsrc,
                    float* __restrict__ aldst,
                    int E_, int N_, int eb) {
  __shared__ float xs[8][33];
  int t = threadIdx.x;
  if (blockIdx.x < (unsigned)eb) {
    int e = blockIdx.x * 256 + t;
    if (e < E_) {
      int pos = rowptr[dst[e]] + ord[e];
      se[pos] = make_int2(src[e], e);   // single 8B scattered write
    }
  } else {
    // ---- prep1: xq1 = bf16(emb[node_ids]); alsrc1/aldst1 = x @ P1 ----
    const float* P = M + 128;
    int n0 = (blockIdx.x - eb) * 8;
    int nl = t >> 5, c = t & 31;
    int n = n0 + nl;
    if (n < N_) {
      float v = emb[(size_t)node_ids[n] * FIN + c];
      xq[(size_t)n * FIN + c] = __float2bfloat16(v);
      xs[nl][c] = v;
    }
    __syncthreads();
    if (t < 64) {
      int nl2 = t >> 3, h = t & 7;
      int n2 = n0 + nl2;
      if (n2 < N_) {
        float sa = 0.f, sd = 0.f;
#pragma unroll
        for (int k = 0; k < FIN; ++k) {
          float x = xs[nl2][k];
          sa = fmaf(x, P[k * 8 + h], sa);
          sd = fmaf(x, P[256 + k * 8 + h], sd);
        }
        alsrc[(size_t)n2 * NH + h] = sa;
        aldst[(size_t)n2 * NH + h] = sd;
      }
    }
  }
}

// pos-order pass: gather edge_attr[e] ONCE (random), fold with M, write
// srcs + per-layer packed bf16 records COALESCED (16B each layer).
__global__ __launch_bounds__(256) void
alepk_build_kernel(const int2* __restrict__ se, const float* __restrict__ edge_attr,
                   const float* __restrict__ M,
                   int* __restrict__ srcs, unsigned int* __restrict__ ale1pk,
                   unsigned int* __restrict__ ale2pk, int E_) {
  __shared__ float Msh[128];
  int t = threadIdx.x;
  if (t < 128) Msh[t] = M[t];
  __syncthreads();
  int pos = blockIdx.x * 256 + t;
  if (pos >= E_) return;
  int2 s2 = se[pos];               // coalesced 8B read
  srcs[pos] = s2.x;                // coalesced 4B write
  int e = s2.y;
  const float4* ep = (const float4*)(edge_attr + (size_t)e * NH);  // 32B gather
  float4 a0 = ep[0], a1 = ep[1];
  float ea[8] = {a0.x, a0.y, a0.z, a0.w, a1.x, a1.y, a1.z, a1.w};
  float o1[8], o2[8];
#pragma unroll
  for (int h = 0; h < 8; ++h) { o1[h] = 0.f; o2[h] = 0.f; }
#pragma unroll
  for (int k = 0; k < 8; ++k) {
    float x = ea[k];
#pragma unroll
    for (int h = 0; h < 8; ++h) {
      o1[h] = fmaf(x, Msh[k * 8 + h], o1[h]);
      o2[h] = fmaf(x, Msh[64 + k * 8 + h], o2[h]);
    }
  }
  uint4 r0 = make_uint4(pk2(o1[0], o1[1]), pk2(o1[2], o1[3]),
                        pk2(o1[4], o1[5]), pk2(o1[6], o1[7]));
  uint4 r1 = make_uint4(pk2(o2[0], o2[1]), pk2(o2[2], o2[3]),
                        pk2(o2[4], o2[5]), pk2(o2[6], o2[7]));
  *(uint4*)(ale1pk + (size_t)pos * 4) = r0;   // coalesced 16B write
  *(uint4*)(ale2pk + (size_t)pos * 4) = r1;   // coalesced 16B write
}

// ---- fused agg: BARRIER-FREE main loop + MFMA z@W epilogue (swizzle-fed) ----
// Main loop identical to the verified R7/R9 structure.
// z is stored XOR-swizzled: float4 #f of node n at byte n*1024 + ((f^n)&63)*16.
// A-frag read (lane row,seg: channels hh*32+seg*8..+7 = float4s f0,f0+1) then
// hits 8 distinct bank groups across rows (was 8-way conflict at stride 1024).
// B-frag comes from fragment-ordered wfrag: ONE coalesced 16B read per lane.
template <int K, int LOG2K, bool LOGITS>
__global__ __launch_bounds__(256, 8) void
agg_kernel(const int* __restrict__ rowptr, const int* __restrict__ srcs,
           const bf16* __restrict__ ale,
           const float* __restrict__ alsrc, const float* __restrict__ aldst,
           const bf16* __restrict__ xq,
           const bf16* __restrict__ Wfrag, const float* __restrict__ b,
           const float* __restrict__ Wlin, const float* __restrict__ blin,
           float* __restrict__ xoutf, bf16* __restrict__ xqn,
           const float* __restrict__ Pn,
           float* __restrict__ alsrcn, float* __restrict__ aldstn, int N_) {
  __shared__ __align__(16) char smem[17408];
  unsigned int* xsu = (unsigned int*)smem;
  float* wsf   = (float*)(smem + 8192);
  float* ald_s = (float*)(smem + 12288);
  float* gs   = (float*)(smem + 8192);
  float* red  = (float*)smem;
  float* xrow = (float*)(smem + 16384);

  int t = threadIdx.x;
  int n0 = blockIdx.x * GROUP;
  int w = t >> 6, l = t & 63, h = l >> 3, q = l & 7;

  unsigned int* xw  = xsu + w * 512;
  float*        wsw = wsf + w * 256;
  char* xwb = smem + w * 2048;     // wave-uniform LDS base for staging

  // this wave's two nodes' edge ranges (wave-uniform scalars)
  int nA = n0 + w * 2;
  int e0  = rowptr[(nA     <= N_) ? nA     : N_];
  int e1  = rowptr[(nA + 1 <= N_) ? nA + 1 : N_];
  int e2g = rowptr[(nA + 2 <= N_) ? nA + 2 : N_];

  if (t < GROUP * NH) {
    int nn = n0 + (t >> 3);
    ald_s[t] = (nn < N_) ? aldst[(size_t)nn * NH + (t & 7)] : 0.f;
  }
  __syncthreads();   // ald_s visible to all waves (read-only afterwards)

  float4 acc0 = make_float4(0.f, 0.f, 0.f, 0.f);
  float4 acc1 = make_float4(0.f, 0.f, 0.f, 0.f);
  float dn0 = 0.f, dn1 = 0.f;

  for (int cbeg = e0; cbeg < e2g; cbeg += CAPW) {
    int clen = e2g - cbeg; if (clen > CAPW) clen = CAPW;

    // stage x rows: 2 passes of 16 edges via global_load_lds (16B/lane)
    {
      int el0 = (l >> 2);
      int coff = (l & 3);
      int ec0 = el0 < clen - 1 ? el0 : clen - 1;          // clamp keeps lanes active
      {
        int s = srcs[cbeg + ec0];
        const bf16* gp = xq + (size_t)s * FIN + coff * 8;
        __builtin_amdgcn_global_load_lds(
            (const __attribute__((address_space(1))) void*)gp,
            (__attribute__((address_space(3))) void*)xwb, 16, 0, 0);
      }
      if (clen > 16) {
        int el1 = 16 + el0;
        int ec1 = el1 < clen - 1 ? el1 : clen - 1;
        int s = srcs[cbeg + ec1];
        const bf16* gp = xq + (size_t)s * FIN + coff * 8;
        __builtin_amdgcn_global_load_lds(
            (const __attribute__((address_space(1))) void*)gp,
            (__attribute__((address_space(3))) void*)(xwb + 1024), 16, 0, 0);
      }
    }
    // stage exp(alpha): 2 lanes/edge; al_e from packed bf16 record (coalesced)
    {
      int e2 = l >> 1, half = l & 1;
      if (e2 < clen) {
        int j = cbeg + e2;
        int ii = (j >= e1) ? 1 : 0;
        int sn = srcs[j];
        uint2 ue  = *(const uint2*)(ale + (size_t)j * 8 + half * 4);
        float4 as4 = *(const float4*)(alsrc + (size_t)sn * NH + half * 4);
        float4 ad4 = *(const float4*)&ald_s[(w * 2 + ii) * 8 + half * 4];
        float a0f = blo(ue.x) + as4.x + ad4.x; a0f = (a0f >= 0.f) ? a0f : 0.2f * a0f;
        float a1f = bhi(ue.x) + as4.y + ad4.y; a1f = (a1f >= 0.f) ? a1f : 0.2f * a1f;
        float a2f = blo(ue.y) + as4.z + ad4.z; a2f = (a2f >= 0.f) ? a2f : 0.2f * a2f;
        float a3f = bhi(ue.y) + as4.w + ad4.w; a3f = (a3f >= 0.f) ? a3f : 0.2f * a3f;
        *(float4*)&wsw[e2 * 8 + half * 4] =
            make_float4(__expf(a0f), __expf(a1f), __expf(a2f), __expf(a3f));
      }
    }
    // wave-local fence: staged x (vmcnt) + exp writes (lgkmcnt) before reads
    asm volatile("s_waitcnt vmcnt(0) lgkmcnt(0)" ::: "memory");

    // FMA: this wave sweeps its staged edges (broadcast LDS reads)
    int hA = e1 - cbeg; if (hA < 0) hA = 0; if (hA > clen) hA = clen;
#pragma unroll 4
    for (int le = 0; le < hA; ++le) {
      float wv = wsw[le * 8 + h];
      uint2 u = *(const uint2*)&xw[le * 16 + q * 2];
      acc0.x = fmaf(blo(u.x), wv, acc0.x);
      acc0.y = fmaf(bhi(u.x), wv, acc0.y);
      acc0.z = fmaf(blo(u.y), wv, acc0.z);
      acc0.w = fmaf(bhi(u.y), wv, acc0.w);
      dn0 += wv;
    }
#pragma unroll 4
    for (int le = hA; le < clen; ++le) {
      float wv = wsw[le * 8 + h];
      uint2 u = *(const uint2*)&xw[le * 16 + q * 2];
      acc1.x = fmaf(blo(u.x), wv, acc1.x);
      acc1.y = fmaf(bhi(u.x), wv, acc1.y);
      acc1.z = fmaf(blo(u.y), wv, acc1.z);
      acc1.w = fmaf(bhi(u.y), wv, acc1.w);
      dn1 += wv;
    }
    asm volatile("s_waitcnt lgkmcnt(0)" ::: "memory");  // reads done before restage
  }

  // normalize + write z XOR-SWIZZLED into this wave's own staging slice:
  // float4 #l (channels 4l..4l+3) of node n at byte n*1024 + ((l^n)&63)*16.
  float rd0 = 1.0f / (dn0 + 1e-16f);
  float rd1 = 1.0f / (dn1 + 1e-16f);
  {
    int na0 = w * 2, na1 = w * 2 + 1;
    *(float4*)(smem + na0 * 1024 + ((l ^ na0) & 63) * 16) =
        make_float4(acc0.x * rd0, acc0.y * rd0, acc0.z * rd0, acc0.w * rd0);
    *(float4*)(smem + na1 * 1024 + ((l ^ na1) & 63) * 16) =
        make_float4(acc1.x * rd1, acc1.y * rd1, acc1.z * rd1, acc1.w * rd1);
  }
  __syncthreads();

  // g = relu(z @ W + b) via MFMA: wave w -> heads 2w, 2w+1; 2 col-tiles each.
  // A-frag: lane (row=l&15, seg=l>>4) holds z[row][hh*32+seg*8+j] (swizzled read).
  // B-frag: one coalesced 16B read from fragment-ordered Wfrag.
  // D: row=(l>>4)*4+r, col=l&15 (C/D mapping HW-verified).
  {
    typedef __attribute__((ext_vector_type(8))) short short8v;
    typedef __attribute__((ext_vector_type(4))) float f32x4v;
    int row = l & 15, seg = l >> 4;
#pragma unroll
    for (int hh2 = 0; hh2 < 2; ++hh2) {
      int hh = w * 2 + hh2;
      short8v af;
      if (row < GROUP) {
        int f0 = hh * 8 + seg * 2;
        float4 za = *(const float4*)(smem + row * 1024 + ((f0 ^ row) & 63) * 16);
        float4 zb = *(const float4*)(smem + row * 1024 + (((f0 + 1) ^ row) & 63) * 16);
        af[0] = bfs(za.x); af[1] = bfs(za.y); af[2] = bfs(za.z); af[3] = bfs(za.w);
        af[4] = bfs(zb.x); af[5] = bfs(zb.y); af[6] = bfs(zb.z); af[7] = bfs(zb.w);
      } else {
#pragma unroll
        for (int j = 0; j < 8; ++j) af[j] = 0;
      }
#pragma unroll
      for (int n2 = 0; n2 < 2; ++n2) {
        int tile = hh * 2 + n2;
        uint4 bw = *(const uint4*)(Wfrag + (size_t)tile * 512 + l * 8);
        short8v bfv;
        __builtin_memcpy(&bfv, &bw, 16);
        f32x4v d = {0.f, 0.f, 0.f, 0.f};
        d = __builtin_amdgcn_mfma_f32_16x16x32_bf16(af, bfv, d, 0, 0, 0);
#pragma unroll
        for (int r = 0; r < 4; ++r) {
          int rd = seg * 4 + r;
          if (rd < GROUP) {
            int tc = hh * 32 + n2 * 16 + row;
            float gv = d[r] + b[tc];
            gs[rd * 256 + tc] = (gv > 0.f) ? gv : 0.f;
          }
        }
      }
    }
  }
  __syncthreads();

  // lin: xout = g @ Wlin + blin (Wlin element reused x GROUP); red aliases zs (dead)
  {
    int kk = t & (K - 1), r = t >> LOG2K;
    float part[GROUP];
#pragma unroll
    for (int i = 0; i < GROUP; ++i) part[i] = 0.f;
#pragma unroll
    for (int j4 = 0; j4 < K / 4; ++j4) {
      float ga[GROUP][4];
#pragma unroll
      for (int i = 0; i < GROUP; ++i)
        *(float4*)ga[i] = *(const float4*)&gs[i * 256 + r * K + j4 * 4];
#pragma unroll
      for (int jj = 0; jj < 4; ++jj) {
        float wl = Wlin[(r * K + j4 * 4 + jj) * K + kk];
#pragma unroll
        for (int i = 0; i < GROUP; ++i) part[i] = fmaf(ga[i][jj], wl, part[i]);
      }
    }
#pragma unroll
    for (int i = 0; i < GROUP; ++i) red[i * 256 + t] = part[i];
  }
  __syncthreads();

  if (LOGITS) {
    if (t < GROUP * 32) {
      int i = t >> 5, kk = t & 31;
      float s = blin[kk];
#pragma unroll
      for (int r2 = 0; r2 < HC / K; ++r2) s += red[i * 256 + r2 * K + kk];
      int nn = n0 + i;
      if (nn < N_) xqn[(size_t)nn * FIN + kk] = __float2bfloat16(s);
      xrow[t] = s;
    }
    __syncthreads();
    if (t < GROUP * NH) {
      int i = t >> 3, hh = t & 7;
      int nn = n0 + i;
      if (nn < N_) {
        float sa = 0.f, sd = 0.f;
#pragma unroll
        for (int k2 = 0; k2 < FIN; ++k2) {
          float x = xrow[i * 32 + k2];
          sa = fmaf(x, Pn[k2 * 8 + hh], sa);
          sd = fmaf(x, Pn[256 + k2 * 8 + hh], sd);
        }
        alsrcn[(size_t)nn * NH + hh] = sa;
        aldstn[(size_t)nn * NH + hh] = sd;
      }
    }
  } else {
    if (t < GROUP * K) {
      int i = t >> LOG2K, kk = t & (K - 1);
      float s = blin[kk];
#pragma unroll
      for (int r2 = 0; r2 < HC / K; ++r2) s += red[i * 256 + r2 * K + kk];
      int nn = n0 + i;
      if (nn < N_) xoutf[(size_t)nn * K + kk] = s;
    }
  }
}

// ---------------- classifier: sigmoid(sum(fu*fm)) ----------------------------
__global__ void clf_kernel(const int* __restrict__ eli, const float* __restrict__ ela,
                           const float* __restrict__ x2, const float* __restrict__ clfW,
                           const float* __restrict__ clfb, float* __restrict__ out, int L_) {
  int i = blockIdx.x * blockDim.x + threadIdx.x;
  if (i >= L_) return;
  int u = eli[i], m = eli[L_ + i];
  const float4* xup = (const float4*)(x2 + (size_t)u * NH);
  const float4* xmp = (const float4*)(x2 + (size_t)m * NH);
  const float4* eap = (const float4*)(ela + (size_t)i * NH);
  float4 xu0 = xup[0], xu1 = xup[1];
  float4 xm0 = xmp[0], xm1 = xmp[1];
  float4 el0 = eap[0], el1 = eap[1];
  float xu[NH] = {xu0.x, xu0.y, xu0.z, xu0.w, xu1.x, xu1.y, xu1.z, xu1.w};
  float xm[NH] = {xm0.x, xm0.y, xm0.z, xm0.w, xm1.x, xm1.y, xm1.z, xm1.w};
  float el[NH] = {el0.x, el0.y, el0.z, el0.w, el1.x, el1.y, el1.z, el1.w};
  float fu[NH];
#pragma unroll
  for (int kk = 0; kk < NH; ++kk) fu[kk] = clfb[kk];
#pragma unroll
  for (int j = 0; j < NH; ++j) {
#pragma unroll
    for (int kk = 0; kk < NH; ++kk) fu[kk] = fmaf(xu[j], clfW[j * NH + kk], fu[kk]);
  }
#pragma unroll
  for (int j = 0; j < NH; ++j) {
#pragma unroll
    for (int kk = 0; kk < NH; ++kk) fu[kk] = fmaf(el[j], clfW[(NH + j) * NH + kk], fu[kk]);
  }
  float dot = 0.f;
#pragma unroll
  for (int kk = 0; kk < NH; ++kk) dot += fu[kk] * xm[kk];
  out[i] = 1.f / (1.f + __expf(-dot));
}

extern "C" void kernel_launch(void* const* d_in, const int* in_sizes, int n_in,
                              void* d_out, int out_size, void* d_ws, size_t ws_size,
                              hipStream_t stream) {
  const int* node_ids   = (const int*)d_in[0];
  const int* edge_index = (const int*)d_in[1];
  const int* eli        = (const int*)d_in[2];
  const float* edge_attr = (const float*)d_in[4];
  const float* ela       = (const float*)d_in[5];
  const float* emb       = (const float*)d_in[6];
  const float* W1     = (const float*)d_in[7];
  const float* a_src1 = (const float*)d_in[8];
  const float* a_dst1 = (const float*)d_in[9];
  const float* We1    = (const float*)d_in[10];
  const float* a_e1   = (const float*)d_in[11];
  const float* b1     = (const float*)d_in[12];
  const float* lin1W  = (const float*)d_in[13];
  const float* lin1b  = (const float*)d_in[14];
  const float* W2     = (const float*)d_in[15];
  const float* a_src2 = (const float*)d_in[16];
  const float* a_dst2 = (const float*)d_in[17];
  const float* We2    = (const float*)d_in[18];
  const float* a_e2   = (const float*)d_in[19];
  const float* b2     = (const float*)d_in[20];
  const float* lin5W  = (const float*)d_in[21];
  const float* lin5b  = (const float*)d_in[22];
  const float* clfW   = (const float*)d_in[23];
  const float* clfb   = (const float*)d_in[24];

  const int N_ = in_sizes[0];
  const int E_ = in_sizes[1] / 2;
  const int L_ = in_sizes[2] / 2;
  const int* src  = edge_index;
  const int* dstp = edge_index + E_;

  char* p = (char*)d_ws;
  auto carve = [&](size_t bytes) -> char* {
    char* r = p;
    p += (bytes + 255) & ~(size_t)255;
    return r;
  };
  bf16*  xq1     = (bf16*)carve((size_t)N_ * FIN * 2);
  bf16*  xq2     = (bf16*)carve((size_t)N_ * FIN * 2);
  unsigned int* ale1pk = (unsigned int*)carve((size_t)E_ * 16);  // 12.8 MB packed bf16
  unsigned int* ale2pk = (unsigned int*)carve((size_t)E_ * 16);  // 12.8 MB packed bf16
  float* alsrc1  = (float*)carve((size_t)N_ * NH * 4);
  float* aldst1  = (float*)carve((size_t)N_ * NH * 4);
  float* alsrc2  = (float*)carve((size_t)N_ * NH * 4);
  float* aldst2  = (float*)carve((size_t)N_ * NH * 4);
  float* x2b     = (float*)carve((size_t)N_ * NH * 4);
  float* Mbuf    = (float*)carve(1152 * 4);
  bf16*  w1frag  = (bf16*)carve(8192 * 2);
  bf16*  w2frag  = (bf16*)carve(8192 * 2);
  int*   cnt     = (int*)carve((size_t)N_ * 4);
  int*   rowptr  = (int*)carve((size_t)(N_ + 1) * 4);
  int*   stmp    = (int*)carve((size_t)N_ * 4);
  int*   bsum    = (int*)carve(1024 * 4);
  int*   srcs    = (int*)carve((size_t)E_ * 4);
  int*   ordb    = (int*)carve((size_t)E_ * 4);
  int2*  se      = (int2*)carve((size_t)E_ * 8);

  hipMemsetAsync(cnt, 0, (size_t)N_ * 4, stream);
  int eb = (E_ + 255) / 256;
  int nb = (N_ + 255) / 256;
  int pb = (N_ + 7) / 8;
  count_fold_kernel<<<eb + 1, 256, 0, stream>>>(dstp, cnt, ordb, E_, eb,
                                                We1, a_e1, We2, a_e2,
                                                W1, a_src1, a_dst1,
                                                W2, a_src2, a_dst2, Mbuf,
                                                w1frag, w2frag);
  scan_partial<<<nb, 256, 0, stream>>>(cnt, stmp, bsum, N_);
  scan_final<<<nb, 256, 0, stream>>>(cnt, stmp, bsum, rowptr, N_, E_, nb);
  scatter_prep_kernel<<<eb + pb, 256, 0, stream>>>(
      src, dstp, rowptr, ordb, se, Mbuf,
      emb, node_ids, xq1, alsrc1, aldst1, E_, N_, eb);
  alepk_build_kernel<<<eb, 256, 0, stream>>>(se, edge_attr, Mbuf, srcs,
                                             ale1pk, ale2pk, E_);

  int gb = (N_ + GROUP - 1) / GROUP;
  // ---- layer 1 (fully fused) ----
  agg_kernel<32, 5, true><<<gb, 256, 0, stream>>>(
      rowptr, srcs, (const bf16*)ale1pk, alsrc1, aldst1, xq1,
      w1frag, b1, lin1W, lin1b, nullptr, xq2, Mbuf + 640, alsrc2, aldst2, N_);

  // ---- layer 2 ----
  agg_kernel<8, 3, false><<<gb, 256, 0, stream>>>(
      rowptr, srcs, (const bf16*)ale2pk, alsrc2, aldst2, xq2,
      w2frag, b2, lin5W, lin5b, x2b, nullptr, nullptr, nullptr, nullptr, N_);

  // ---- classifier ----
  clf_kernel<<<(L_ + 255) / 256, 256, 0, stream>>>(eli, ela, x2b, clfW, clfb,
                                                   (float*)d_out, L_);
}

// Round 12
// 316.698 us; speedup vs baseline: 1.0261x; 1.0059x over previous
//
#include <hip/hip_runtime.h>
#include <hip/hip_bf16.h>

#define HC    256
#define FIN   32
#define NH    8
#define GROUP 8     // dst nodes per block (2 per wave)
#define CAPW  32    // per-wave staged edges per chunk

typedef __hip_bfloat16 bf16;

__device__ __forceinline__ float blo(unsigned int u) { return __uint_as_float(u << 16); }
__device__ __forceinline__ float bhi(unsigned int u) { return __uint_as_float(u & 0xffff0000u); }
__device__ __forceinline__ unsigned int pk2(float a, float b) {
  bf16 ha = __float2bfloat16(a), hb = __float2bfloat16(b);
  unsigned short ua, ub;
  __builtin_memcpy(&ua, &ha, 2); __builtin_memcpy(&ub, &hb, 2);
  return (unsigned int)ua | ((unsigned int)ub << 16);
}
__device__ __forceinline__ short bfs(float v) {
  bf16 h = __float2bfloat16(v);
  short s; __builtin_memcpy(&s, &h, 2);
  return s;
}

// ---------------- CSR build ---------------------------------------------------
// blocks [0,eb): count + per-edge rank (coalesced ord write).
// block eb: folded weight prep + FRAGMENT-ORDERED bf16 W for the MFMA epilogue.
// wfrag layout: [tile=hh*2+n2][lane=seg*16+row][j=0..7] bf16, value =
//   W[(seg*8+j)*HC + hh*32 + n2*16 + row]  (B-frag layout verified in R10/R11:
//   absmax unchanged vs pure-VALU epilogue).
__global__ void count_fold_kernel(const int* __restrict__ dst, int* __restrict__ cnt,
                                  int* __restrict__ ord, int E_, int eb,
                                  const float* __restrict__ We1, const float* __restrict__ ae1,
                                  const float* __restrict__ We2, const float* __restrict__ ae2,
                                  const float* __restrict__ W1, const float* __restrict__ as1,
                                  const float* __restrict__ ad1,
                                  const float* __restrict__ W2, const float* __restrict__ as2,
                                  const float* __restrict__ ad2,
                                  float* __restrict__ M,
                                  bf16* __restrict__ w1frag, bf16* __restrict__ w2frag) {
  if (blockIdx.x < (unsigned)eb) {
    int e = blockIdx.x * blockDim.x + threadIdx.x;
    if (e < E_) ord[e] = atomicAdd(&cnt[dst[e]], 1);
  } else {
    for (int idx = threadIdx.x; idx < 1152; idx += 256) {
      const float* A; const float* V; int i;
      if (idx < 64)       { i = idx;       A = We1; V = ae1; }
      else if (idx < 128) { i = idx - 64;  A = We2; V = ae2; }
      else if (idx < 384) { i = idx - 128; A = W1;  V = as1; }
      else if (idx < 640) { i = idx - 384; A = W1;  V = ad1; }
      else if (idx < 896) { i = idx - 640; A = W2;  V = as2; }
      else                { i = idx - 896; A = W2;  V = ad2; }
      int k = i >> 3, h = i & 7;
      float s = 0.f;
      for (int c = 0; c < FIN; ++c)
        s = fmaf(A[k * HC + h * FIN + c], V[h * FIN + c], s);
      M[idx] = s;
    }
    // fragment-ordered bf16 W1/W2 (16 tiles x 64 lanes x 8 = 8192 elems each)
    for (int idx = threadIdx.x; idx < 8192; idx += 256) {
      int j = idx & 7, lane = (idx >> 3) & 63, tile = idx >> 9;
      int seg = lane >> 4, row = lane & 15;
      int hh = tile >> 1, n2 = tile & 1;
      int k = seg * 8 + j, col = hh * 32 + n2 * 16 + row;
      w1frag[idx] = __float2bfloat16(W1[k * HC + col]);
      w2frag[idx] = __float2bfloat16(W2[k * HC + col]);
    }
  }
}

// scan step 1: per-256-tile inclusive prefix (into tmp) + raw tile sums (bsum)
__global__ __launch_bounds__(256) void
scan_partial(const int* __restrict__ cnt, int* __restrict__ tmp,
             int* __restrict__ bsum, int N_) {
  __shared__ int part[256];
  int t = threadIdx.x, i = blockIdx.x * 256 + t;
  int v = (i < N_) ? cnt[i] : 0;
  part[t] = v;
  __syncthreads();
#pragma unroll
  for (int off = 1; off < 256; off <<= 1) {
    int u = (t >= off) ? part[t - off] : 0;
    __syncthreads();
    part[t] += u;
    __syncthreads();
  }
  if (i < N_) tmp[i] = part[t];
  if (t == 255) bsum[blockIdx.x] = part[255];
}

// scan step 2 (fused): each block reduces bsum[0..bid) itself, then
// rowptr[i] = boff + incl[i] - cnt[i]; rowptr[N]=E. (NB <= ~1024 is cheap.)
__global__ __launch_bounds__(256) void
scan_final(const int* __restrict__ cnt, const int* __restrict__ tmp,
           const int* __restrict__ bsum, int* __restrict__ rowptr,
           int N_, int E_, int NB) {
  __shared__ int red[256];
  int t = threadIdx.x, b = blockIdx.x;
  int acc = 0;
  for (int j = t; j < b; j += 256) acc += bsum[j];
  red[t] = acc;
  __syncthreads();
#pragma unroll
  for (int off = 128; off > 0; off >>= 1) {
    if (t < off) red[t] += red[t + off];
    __syncthreads();
  }
  int boff = red[0];
  int i = b * 256 + t;
  if (i < N_) rowptr[i] = boff + tmp[i] - cnt[i];
  if (i == 0) rowptr[N_] = E_;
}

// scatter-lite (no atomics, ONE 8B scattered write/edge) + fused layer-1 prep.
// Blocks [0, eb): se[pos] = {src[e], e}. Blocks [eb, eb+pb): prep1.
__global__ __launch_bounds__(256) void
scatter_prep_kernel(const int* __restrict__ src, const int* __restrict__ dst,
                    const int* __restrict__ rowptr, const int* __restrict__ ord,
                    int2* __restrict__ se,
                    const float* __restrict__ M,
                    const float* __restrict__ emb, const int* __restrict__ node_ids,
                    bf16* __restrict__ xq, float* __restrict__ alsrc,
                    float* __restrict__ aldst,
                    int E_, int N_, int eb) {
  __shared__ float xs[8][33];
  int t = threadIdx.x;
  if (blockIdx.x < (unsigned)eb) {
    int e = blockIdx.x * 256 + t;
    if (e < E_) {
      int pos = rowptr[dst[e]] + ord[e];
      se[pos] = make_int2(src[e], e);   // single 8B scattered write
    }
  } else {
    // ---- prep1: xq1 = bf16(emb[node_ids]); alsrc1/aldst1 = x @ P1 ----
    const float* P = M + 128;
    int n0 = (blockIdx.x - eb) * 8;
    int nl = t >> 5, c = t & 31;
    int n = n0 + nl;
    if (n < N_) {
      float v = emb[(size_t)node_ids[n] * FIN + c];
      xq[(size_t)n * FIN + c] = __float2bfloat16(v);
      xs[nl][c] = v;
    }
    __syncthreads();
    if (t < 64) {
      int nl2 = t >> 3, h = t & 7;
      int n2 = n0 + nl2;
      if (n2 < N_) {
        float sa = 0.f, sd = 0.f;
#pragma unroll
        for (int k = 0; k < FIN; ++k) {
          float x = xs[nl2][k];
          sa = fmaf(x, P[k * 8 + h], sa);
          sd = fmaf(x, P[256 + k * 8 + h], sd);
        }
        alsrc[(size_t)n2 * NH + h] = sa;
        aldst[(size_t)n2 * NH + h] = sd;
      }
    }
  }
}

// pos-order pass: gather edge_attr[e] ONCE (random), fold with M, write
// srcs + per-layer packed bf16 records COALESCED (16B each layer).
__global__ __launch_bounds__(256) void
alepk_build_kernel(const int2* __restrict__ se, const float* __restrict__ edge_attr,
                   const float* __restrict__ M,
                   int* __restrict__ srcs, unsigned int* __restrict__ ale1pk,
                   unsigned int* __restrict__ ale2pk, int E_) {
  __shared__ float Msh[128];
  int t = threadIdx.x;
  if (t < 128) Msh[t] = M[t];
  __syncthreads();
  int pos = blockIdx.x * 256 + t;
  if (pos >= E_) return;
  int2 s2 = se[pos];               // coalesced 8B read
  srcs[pos] = s2.x;                // coalesced 4B write
  int e = s2.y;
  const float4* ep = (const float4*)(edge_attr + (size_t)e * NH);  // 32B gather
  float4 a0 = ep[0], a1 = ep[1];
  float ea[8] = {a0.x, a0.y, a0.z, a0.w, a1.x, a1.y, a1.z, a1.w};
  float o1[8], o2[8];
#pragma unroll
  for (int h = 0; h < 8; ++h) { o1[h] = 0.f; o2[h] = 0.f; }
#pragma unroll
  for (int k = 0; k < 8; ++k) {
    float x = ea[k];
#pragma unroll
    for (int h = 0; h < 8; ++h) {
      o1[h] = fmaf(x, Msh[k * 8 + h], o1[h]);
      o2[h] = fmaf(x, Msh[64 + k * 8 + h], o2[h]);
    }
  }
  uint4 r0 = make_uint4(pk2(o1[0], o1[1]), pk2(o1[2], o1[3]),
                        pk2(o1[4], o1[5]), pk2(o1[6], o1[7]));
  uint4 r1 = make_uint4(pk2(o2[0], o2[1]), pk2(o2[2], o2[3]),
                        pk2(o2[4], o2[5]), pk2(o2[6], o2[7]));
  *(uint4*)(ale1pk + (size_t)pos * 4) = r0;   // coalesced 16B write
  *(uint4*)(ale2pk + (size_t)pos * 4) = r1;   // coalesced 16B write
}

// ---- fused agg: BARRIER-FREE main loop + MFMA z@W epilogue (swizzle-fed) ----
// Identical to R11 except __launch_bounds__(256, 6): VGPR cap 64 -> 85 so the
// MFMA-epilogue temporaries (za/zb/af/bfv/d) stay in registers instead of
// spilling to scratch (suspected source of the +25MB WRITE_SIZE anomaly).
template <int K, int LOG2K, bool LOGITS>
__global__ __launch_bounds__(256, 6) void
agg_kernel(const int* __restrict__ rowptr, const int* __restrict__ srcs,
           const bf16* __restrict__ ale,
           const float* __restrict__ alsrc, const float* __restrict__ aldst,
           const bf16* __restrict__ xq,
           const bf16* __restrict__ Wfrag, const float* __restrict__ b,
           const float* __restrict__ Wlin, const float* __restrict__ blin,
           float* __restrict__ xoutf, bf16* __restrict__ xqn,
           const float* __restrict__ Pn,
           float* __restrict__ alsrcn, float* __restrict__ aldstn, int N_) {
  __shared__ __align__(16) char smem[17408];
  unsigned int* xsu = (unsigned int*)smem;
  float* wsf   = (float*)(smem + 8192);
  float* ald_s = (float*)(smem + 12288);
  float* gs   = (float*)(smem + 8192);
  float* red  = (float*)smem;
  float* xrow = (float*)(smem + 16384);

  int t = threadIdx.x;
  int n0 = blockIdx.x * GROUP;
  int w = t >> 6, l = t & 63, h = l >> 3, q = l & 7;

  unsigned int* xw  = xsu + w * 512;
  float*        wsw = wsf + w * 256;
  char* xwb = smem + w * 2048;     // wave-uniform LDS base for staging

  // this wave's two nodes' edge ranges (wave-uniform scalars)
  int nA = n0 + w * 2;
  int e0  = rowptr[(nA     <= N_) ? nA     : N_];
  int e1  = rowptr[(nA + 1 <= N_) ? nA + 1 : N_];
  int e2g = rowptr[(nA + 2 <= N_) ? nA + 2 : N_];

  if (t < GROUP * NH) {
    int nn = n0 + (t >> 3);
    ald_s[t] = (nn < N_) ? aldst[(size_t)nn * NH + (t & 7)] : 0.f;
  }
  __syncthreads();   // ald_s visible to all waves (read-only afterwards)

  float4 acc0 = make_float4(0.f, 0.f, 0.f, 0.f);
  float4 acc1 = make_float4(0.f, 0.f, 0.f, 0.f);
  float dn0 = 0.f, dn1 = 0.f;

  for (int cbeg = e0; cbeg < e2g; cbeg += CAPW) {
    int clen = e2g - cbeg; if (clen > CAPW) clen = CAPW;

    // stage x rows: 2 passes of 16 edges via global_load_lds (16B/lane)
    {
      int el0 = (l >> 2);
      int coff = (l & 3);
      int ec0 = el0 < clen - 1 ? el0 : clen - 1;          // clamp keeps lanes active
      {
        int s = srcs[cbeg + ec0];
        const bf16* gp = xq + (size_t)s * FIN + coff * 8;
        __builtin_amdgcn_global_load_lds(
            (const __attribute__((address_space(1))) void*)gp,
            (__attribute__((address_space(3))) void*)xwb, 16, 0, 0);
      }
      if (clen > 16) {
        int el1 = 16 + el0;
        int ec1 = el1 < clen - 1 ? el1 : clen - 1;
        int s = srcs[cbeg + ec1];
        const bf16* gp = xq + (size_t)s * FIN + coff * 8;
        __builtin_amdgcn_global_load_lds(
            (const __attribute__((address_space(1))) void*)gp,
            (__attribute__((address_space(3))) void*)(xwb + 1024), 16, 0, 0);
      }
    }
    // stage exp(alpha): 2 lanes/edge; al_e from packed bf16 record (coalesced)
    {
      int e2 = l >> 1, half = l & 1;
      if (e2 < clen) {
        int j = cbeg + e2;
        int ii = (j >= e1) ? 1 : 0;
        int sn = srcs[j];
        uint2 ue  = *(const uint2*)(ale + (size_t)j * 8 + half * 4);
        float4 as4 = *(const float4*)(alsrc + (size_t)sn * NH + half * 4);
        float4 ad4 = *(const float4*)&ald_s[(w * 2 + ii) * 8 + half * 4];
        float a0f = blo(ue.x) + as4.x + ad4.x; a0f = (a0f >= 0.f) ? a0f : 0.2f * a0f;
        float a1f = bhi(ue.x) + as4.y + ad4.y; a1f = (a1f >= 0.f) ? a1f : 0.2f * a1f;
        float a2f = blo(ue.y) + as4.z + ad4.z; a2f = (a2f >= 0.f) ? a2f : 0.2f * a2f;
        float a3f = bhi(ue.y) + as4.w + ad4.w; a3f = (a3f >= 0.f) ? a3f : 0.2f * a3f;
        *(float4*)&wsw[e2 * 8 + half * 4] =
            make_float4(__expf(a0f), __expf(a1f), __expf(a2f), __expf(a3f));
      }
    }
    // wave-local fence: staged x (vmcnt) + exp writes (lgkmcnt) before reads
    asm volatile("s_waitcnt vmcnt(0) lgkmcnt(0)" ::: "memory");

    // FMA: this wave sweeps its staged edges (broadcast LDS reads)
    int hA = e1 - cbeg; if (hA < 0) hA = 0; if (hA > clen) hA = clen;
#pragma unroll 4
    for (int le = 0; le < hA; ++le) {
      float wv = wsw[le * 8 + h];
      uint2 u = *(const uint2*)&xw[le * 16 + q * 2];
      acc0.x = fmaf(blo(u.x), wv, acc0.x);
      acc0.y = fmaf(bhi(u.x), wv, acc0.y);
      acc0.z = fmaf(blo(u.y), wv, acc0.z);
      acc0.w = fmaf(bhi(u.y), wv, acc0.w);
      dn0 += wv;
    }
#pragma unroll 4
    for (int le = hA; le < clen; ++le) {
      float wv = wsw[le * 8 + h];
      uint2 u = *(const uint2*)&xw[le * 16 + q * 2];
      acc1.x = fmaf(blo(u.x), wv, acc1.x);
      acc1.y = fmaf(bhi(u.x), wv, acc1.y);
      acc1.z = fmaf(blo(u.y), wv, acc1.z);
      acc1.w = fmaf(bhi(u.y), wv, acc1.w);
      dn1 += wv;
    }
    asm volatile("s_waitcnt lgkmcnt(0)" ::: "memory");  // reads done before restage
  }

  // normalize + write z XOR-SWIZZLED into this wave's own staging slice:
  // float4 #l (channels 4l..4l+3) of node n at byte n*1024 + ((l^n)&63)*16.
  float rd0 = 1.0f / (dn0 + 1e-16f);
  float rd1 = 1.0f / (dn1 + 1e-16f);
  {
    int na0 = w * 2, na1 = w * 2 + 1;
    *(float4*)(smem + na0 * 1024 + ((l ^ na0) & 63) * 16) =
        make_float4(acc0.x * rd0, acc0.y * rd0, acc0.z * rd0, acc0.w * rd0);
    *(float4*)(smem + na1 * 1024 + ((l ^ na1) & 63) * 16) =
        make_float4(acc1.x * rd1, acc1.y * rd1, acc1.z * rd1, acc1.w * rd1);
  }
  __syncthreads();

  // g = relu(z @ W + b) via MFMA: wave w -> heads 2w, 2w+1; 2 col-tiles each.
  // A-frag: lane (row=l&15, seg=l>>4) holds z[row][hh*32+seg*8+j] (swizzled read).
  // B-frag: one coalesced 16B read from fragment-ordered Wfrag.
  // D: row=(l>>4)*4+r, col=l&15 (C/D mapping HW-verified).
  {
    typedef __attribute__((ext_vector_type(8))) short short8v;
    typedef __attribute__((ext_vector_type(4))) float f32x4v;
    int row = l & 15, seg = l >> 4;
#pragma unroll
    for (int hh2 = 0; hh2 < 2; ++hh2) {
      int hh = w * 2 + hh2;
      short8v af;
      if (row < GROUP) {
        int f0 = hh * 8 + seg * 2;
        float4 za = *(const float4*)(smem + row * 1024 + ((f0 ^ row) & 63) * 16);
        float4 zb = *(const float4*)(smem + row * 1024 + (((f0 + 1) ^ row) & 63) * 16);
        af[0] = bfs(za.x); af[1] = bfs(za.y); af[2] = bfs(za.z); af[3] = bfs(za.w);
        af[4] = bfs(zb.x); af[5] = bfs(zb.y); af[6] = bfs(zb.z); af[7] = bfs(zb.w);
      } else {
#pragma unroll
        for (int j = 0; j < 8; ++j) af[j] = 0;
      }
#pragma unroll
      for (int n2 = 0; n2 < 2; ++n2) {
        int tile = hh * 2 + n2;
        uint4 bw = *(const uint4*)(Wfrag + (size_t)tile * 512 + l * 8);
        short8v bfv;
        __builtin_memcpy(&bfv, &bw, 16);
        f32x4v d = {0.f, 0.f, 0.f, 0.f};
        d = __builtin_amdgcn_mfma_f32_16x16x32_bf16(af, bfv, d, 0, 0, 0);
#pragma unroll
        for (int r = 0; r < 4; ++r) {
          int rd = seg * 4 + r;
          if (rd < GROUP) {
            int tc = hh * 32 + n2 * 16 + row;
            float gv = d[r] + b[tc];
            gs[rd * 256 + tc] = (gv > 0.f) ? gv : 0.f;
          }
        }
      }
    }
  }
  __syncthreads();

  // lin: xout = g @ Wlin + blin (Wlin element reused x GROUP); red aliases zs (dead)
  {
    int kk = t & (K - 1), r = t >> LOG2K;
    float part[GROUP];
#pragma unroll
    for (int i = 0; i < GROUP; ++i) part[i] = 0.f;
#pragma unroll
    for (int j4 = 0; j4 < K / 4; ++j4) {
      float ga[GROUP][4];
#pragma unroll
      for (int i = 0; i < GROUP; ++i)
        *(float4*)ga[i] = *(const float4*)&gs[i * 256 + r * K + j4 * 4];
#pragma unroll
      for (int jj = 0; jj < 4; ++jj) {
        float wl = Wlin[(r * K + j4 * 4 + jj) * K + kk];
#pragma unroll
        for (int i = 0; i < GROUP; ++i) part[i] = fmaf(ga[i][jj], wl, part[i]);
      }
    }
#pragma unroll
    for (int i = 0; i < GROUP; ++i) red[i * 256 + t] = part[i];
  }
  __syncthreads();

  if (LOGITS) {
    if (t < GROUP * 32) {
      int i = t >> 5, kk = t & 31;
      float s = blin[kk];
#pragma unroll
      for (int r2 = 0; r2 < HC / K; ++r2) s += red[i * 256 + r2 * K + kk];
      int nn = n0 + i;
      if (nn < N_) xqn[(size_t)nn * FIN + kk] = __float2bfloat16(s);
      xrow[t] = s;
    }
    __syncthreads();
    if (t < GROUP * NH) {
      int i = t >> 3, hh = t & 7;
      int nn = n0 + i;
      if (nn < N_) {
        float sa = 0.f, sd = 0.f;
#pragma unroll
        for (int k2 = 0; k2 < FIN; ++k2) {
          float x = xrow[i * 32 + k2];
          sa = fmaf(x, Pn[k2 * 8 + hh], sa);
          sd = fmaf(x, Pn[256 + k2 * 8 + hh], sd);
        }
        alsrcn[(size_t)nn * NH + hh] = sa;
        aldstn[(size_t)nn * NH + hh] = sd;
      }
    }
  } else {
    if (t < GROUP * K) {
      int i = t >> LOG2K, kk = t & (K - 1);
      float s = blin[kk];
#pragma unroll
      for (int r2 = 0; r2 < HC / K; ++r2) s += red[i * 256 + r2 * K + kk];
      int nn = n0 + i;
      if (nn < N_) xoutf[(size_t)nn * K + kk] = s;
    }
  }
}

// ---------------- classifier: sigmoid(sum(fu*fm)) ----------------------------
__global__ void clf_kernel(const int* __restrict__ eli, const float* __restrict__ ela,
                           const float* __restrict__ x2, const float* __restrict__ clfW,
                           const float* __restrict__ clfb, float* __restrict__ out, int L_) {
  int i = blockIdx.x * blockDim.x + threadIdx.x;
  if (i >= L_) return;
  int u = eli[i], m = eli[L_ + i];
  const float4* xup = (const float4*)(x2 + (size_t)u * NH);
  const float4* xmp = (const float4*)(x2 + (size_t)m * NH);
  const float4* eap = (const float4*)(ela + (size_t)i * NH);
  float4 xu0 = xup[0], xu1 = xup[1];
  float4 xm0 = xmp[0], xm1 = xmp[1];
  float4 el0 = eap[0], el1 = eap[1];
  float xu[NH] = {xu0.x, xu0.y, xu0.z, xu0.w, xu1.x, xu1.y, xu1.z, xu1.w};
  float xm[NH] = {xm0.x, xm0.y, xm0.z, xm0.w, xm1.x, xm1.y, xm1.z, xm1.w};
  float el[NH] = {el0.x, el0.y, el0.z, el0.w, el1.x, el1.y, el1.z, el1.w};
  float fu[NH];
#pragma unroll
  for (int kk = 0; kk < NH; ++kk) fu[kk] = clfb[kk];
#pragma unroll
  for (int j = 0; j < NH; ++j) {
#pragma unroll
    for (int kk = 0; kk < NH; ++kk) fu[kk] = fmaf(xu[j], clfW[j * NH + kk], fu[kk]);
  }
#pragma unroll
  for (int j = 0; j < NH; ++j) {
#pragma unroll
    for (int kk = 0; kk < NH; ++kk) fu[kk] = fmaf(el[j], clfW[(NH + j) * NH + kk], fu[kk]);
  }
  float dot = 0.f;
#pragma unroll
  for (int kk = 0; kk < NH; ++kk) dot += fu[kk] * xm[kk];
  out[i] = 1.f / (1.f + __expf(-dot));
}

extern "C" void kernel_launch(void* const* d_in, const int* in_sizes, int n_in,
                              void* d_out, int out_size, void* d_ws, size_t ws_size,
                              hipStream_t stream) {
  const int* node_ids   = (const int*)d_in[0];
  const int* edge_index = (const int*)d_in[1];
  const int* eli        = (const int*)d_in[2];
  const float* edge_attr = (const float*)d_in[4];
  const float* ela       = (const float*)d_in[5];
  const float* emb       = (const float*)d_in[6];
  const float* W1     = (const float*)d_in[7];
  const float* a_src1 = (const float*)d_in[8];
  const float* a_dst1 = (const float*)d_in[9];
  const float* We1    = (const float*)d_in[10];
  const float* a_e1   = (const float*)d_in[11];
  const float* b1     = (const float*)d_in[12];
  const float* lin1W  = (const float*)d_in[13];
  const float* lin1b  = (const float*)d_in[14];
  const float* W2     = (const float*)d_in[15];
  const float* a_src2 = (const float*)d_in[16];
  const float* a_dst2 = (const float*)d_in[17];
  const float* We2    = (const float*)d_in[18];
  const float* a_e2   = (const float*)d_in[19];
  const float* b2     = (const float*)d_in[20];
  const float* lin5W  = (const float*)d_in[21];
  const float* lin5b  = (const float*)d_in[22];
  const float* clfW   = (const float*)d_in[23];
  const float* clfb   = (const float*)d_in[24];

  const int N_ = in_sizes[0];
  const int E_ = in_sizes[1] / 2;
  const int L_ = in_sizes[2] / 2;
  const int* src  = edge_index;
  const int* dstp = edge_index + E_;

  char* p = (char*)d_ws;
  auto carve = [&](size_t bytes) -> char* {
    char* r = p;
    p += (bytes + 255) & ~(size_t)255;
    return r;
  };
  bf16*  xq1     = (bf16*)carve((size_t)N_ * FIN * 2);
  bf16*  xq2     = (bf16*)carve((size_t)N_ * FIN * 2);
  unsigned int* ale1pk = (unsigned int*)carve((size_t)E_ * 16);  // 12.8 MB packed bf16
  unsigned int* ale2pk = (unsigned int*)carve((size_t)E_ * 16);  // 12.8 MB packed bf16
  float* alsrc1  = (float*)carve((size_t)N_ * NH * 4);
  float* aldst1  = (float*)carve((size_t)N_ * NH * 4);
  float* alsrc2  = (float*)carve((size_t)N_ * NH * 4);
  float* aldst2  = (float*)carve((size_t)N_ * NH * 4);
  float* x2b     = (float*)carve((size_t)N_ * NH * 4);
  float* Mbuf    = (float*)carve(1152 * 4);
  bf16*  w1frag  = (bf16*)carve(8192 * 2);
  bf16*  w2frag  = (bf16*)carve(8192 * 2);
  int*   cnt     = (int*)carve((size_t)N_ * 4);
  int*   rowptr  = (int*)carve((size_t)(N_ + 1) * 4);
  int*   stmp    = (int*)carve((size_t)N_ * 4);
  int*   bsum    = (int*)carve(1024 * 4);
  int*   srcs    = (int*)carve((size_t)E_ * 4);
  int*   ordb    = (int*)carve((size_t)E_ * 4);
  int2*  se      = (int2*)carve((size_t)E_ * 8);

  hipMemsetAsync(cnt, 0, (size_t)N_ * 4, stream);
  int eb = (E_ + 255) / 256;
  int nb = (N_ + 255) / 256;
  int pb = (N_ + 7) / 8;
  count_fold_kernel<<<eb + 1, 256, 0, stream>>>(dstp, cnt, ordb, E_, eb,
                                                We1, a_e1, We2, a_e2,
                                                W1, a_src1, a_dst1,
                                                W2, a_src2, a_dst2, Mbuf,
                                                w1frag, w2frag);
  scan_partial<<<nb, 256, 0, stream>>>(cnt, stmp, bsum, N_);
  scan_final<<<nb, 256, 0, stream>>>(cnt, stmp, bsum, rowptr, N_, E_, nb);
  scatter_prep_kernel<<<eb + pb, 256, 0, stream>>>(
      src, dstp, rowptr, ordb, se, Mbuf,
      emb, node_ids, xq1, alsrc1, aldst1, E_, N_, eb);
  alepk_build_kernel<<<eb, 256, 0, stream>>>(se, edge_attr, Mbuf, srcs,
                                             ale1pk, ale2pk, E_);

  int gb = (N_ + GROUP - 1) / GROUP;
  // ---- layer 1 (fully fused) ----
  agg_kernel<32, 5, true><<<gb, 256, 0, stream>>>(
      rowptr, srcs, (const bf16*)ale1pk, alsrc1, aldst1, xq1,
      w1frag, b1, lin1W, lin1b, nullptr, xq2, Mbuf + 640, alsrc2, aldst2, N_);

  // ---- layer 2 ----
  agg_kernel<8, 3, false><<<gb, 256, 0, stream>>>(
      rowptr, srcs, (const bf16*)ale2pk, alsrc2, aldst2, xq2,
      w2frag, b2, lin5W, lin5b, x2b, nullptr, nullptr, nullptr, nullptr, N_);

  // ---- classifier ----
  clf_kernel<<<(L_ + 255) / 256, 256, 0, stream>>>(eli, ela, x2b, clfW, clfb,
                                                   (float*)d_out, L_);
}